// Round 9
// baseline (394.998 us; speedup 1.0000x reference)
//
#include <hip/hip_runtime.h>
#include <hip/hip_bf16.h>

typedef unsigned short ushort_t;
typedef __attribute__((ext_vector_type(8))) short short8;
typedef __attribute__((ext_vector_type(4))) float f32x4;

#define M_DIM 8192
#define N_DIM 8192
#define K_DIM 2048
#define BM 256
#define BN 256
#define BK 64
#define NT (K_DIM / BK)   // 32 K-tiles

__device__ __forceinline__ ushort_t f2bf(float f) {
    union { float f; unsigned u; } v; v.f = f;
    unsigned r = v.u + 0x7fffu + ((v.u >> 16) & 1u);   // RNE
    return (ushort_t)(r >> 16);
}

__device__ __forceinline__ void async_copy16(const void* g, void* l) {
    __builtin_amdgcn_global_load_lds(
        (const __attribute__((address_space(1))) void*)g,
        (__attribute__((address_space(3))) void*)l, 16, 0, 0);
}

#define BAR() __builtin_amdgcn_s_barrier()
#define LGKM(n) do { asm volatile("s_waitcnt lgkmcnt(" #n ")" ::: "memory"); \
                     __builtin_amdgcn_sched_barrier(0); } while (0)

// ---- kernel 1: x (f32) -> A (bf16) ----
__global__ __launch_bounds__(256) void convert_x(const float* __restrict__ x,
                                                 ushort_t* __restrict__ A) {
    int t = blockIdx.x * 256 + threadIdx.x;
    const float4* p = (const float4*)x + (size_t)t * 2;
    float4 a = p[0], b = p[1];
    short8 o;
    o[0] = (short)f2bf(a.x); o[1] = (short)f2bf(a.y);
    o[2] = (short)f2bf(a.z); o[3] = (short)f2bf(a.w);
    o[4] = (short)f2bf(b.x); o[5] = (short)f2bf(b.y);
    o[6] = (short)f2bf(b.z); o[7] = (short)f2bf(b.w);
    *(short8*)(A + (size_t)t * 8) = o;
}

// ---- kernel 2: codebook gather -> Bt (bf16, N x K layout) ----
__global__ __launch_bounds__(256) void dequant_wt(const int* __restrict__ indices,
                                                  const float* __restrict__ codebook,
                                                  ushort_t* __restrict__ Bt) {
    int g = blockIdx.x;                       // column group 0..1023
    int i = blockIdx.y * 256 + threadIdx.x;   // K row 0..2047
    int idx = indices[(size_t)i * 1024 + g];
    const float4* cb = (const float4*)(codebook + (size_t)idx * 8);
    float4 lo = cb[0], hi = cb[1];
    size_t base = (size_t)g * 8 * K_DIM + i;
    Bt[base + 0 * K_DIM] = f2bf(lo.x);
    Bt[base + 1 * K_DIM] = f2bf(lo.y);
    Bt[base + 2 * K_DIM] = f2bf(lo.z);
    Bt[base + 3 * K_DIM] = f2bf(lo.w);
    Bt[base + 4 * K_DIM] = f2bf(hi.x);
    Bt[base + 5 * K_DIM] = f2bf(hi.y);
    Bt[base + 6 * K_DIM] = f2bf(hi.z);
    Bt[base + 7 * K_DIM] = f2bf(hi.w);
}

// ---- helpers: fragment reads with base + compile-time row offsets ----
__device__ __forceinline__ void read_a(const char* half, int o0, int o1,
                                       short8 (&fr)[4][2]) {
#pragma unroll
    for (int i = 0; i < 4; ++i) {
        fr[i][0] = *(const short8*)(half + o0 + i * 2048);
        fr[i][1] = *(const short8*)(half + o1 + i * 2048);
    }
}

__device__ __forceinline__ void read_b(const char* half, int o0, int o1,
                                       short8 (&fr)[2][2]) {
#pragma unroll
    for (int j = 0; j < 2; ++j) {
        fr[j][0] = *(const short8*)(half + o0 + j * 2048);
        fr[j][1] = *(const short8*)(half + o1 + j * 2048);
    }
}

__device__ __forceinline__ void mfma16(const short8 (&af)[4][2], const short8 (&bf)[2][2],
                                       f32x4 (&acc)[8][4], int I0, int J0) {
    __builtin_amdgcn_s_setprio(1);
#pragma unroll
    for (int kk = 0; kk < 2; ++kk)
#pragma unroll
        for (int i = 0; i < 4; ++i)
#pragma unroll
            for (int j = 0; j < 2; ++j)
                acc[I0 + i][J0 + j] = __builtin_amdgcn_mfma_f32_16x16x32_bf16(
                    af[i][kk], bf[j][kk], acc[I0 + i][J0 + j], 0, 0, 0);
    __builtin_amdgcn_s_setprio(0);
}

// ---- kernel 3: C = A(MxK) * Bt(NxK)^T + bias ; 256^2 tile ----
// R9: 1-phase read-ahead — no MFMA waits on same-phase reads.
//   P1: compute(m0n0: afX,bf0c)  reads B1(g)      stage A(g+1) both halves
//   P2: compute(m0n1: afX,bf1)   reads A1(g)->afY
//   P3: compute(m1n1: afY,bf1)                    stage B(g+2,0)
//   P4: compute(m1n0: afY,bf0c)  reads A0(g+1)->afX, B0(g+1)->bf0n ; stage B(g+2,1)
// Waits: P1 lgkm(4) [retire afX,bf0n of prev P4; leave bf1]; P2 lgkm(8)
// [retire bf1; leave afY]; P3 lgkm(0) [afY]; P4 none (deps drained at P3).
// vmcnt(4) at P4 retires exactly {B(g+1), A(g+1)}; tail g>=NT-2 -> vmcnt(0).
__global__ __launch_bounds__(512, 2) void gemm_256_8phase(const ushort_t* __restrict__ A,
                                                          const ushort_t* __restrict__ Bt,
                                                          const float* __restrict__ bias,
                                                          float* __restrict__ C) {
    __shared__ __align__(16) ushort_t lds_a[2][2][128 * 64];
    __shared__ __align__(16) ushort_t lds_b[2][2][128 * 64];

    // 2D XCD-rectangle swizzle (R5)
    const int bid = blockIdx.x;                  // 0..1023
    const int x = bid & 7;                       // XCD
    const int q = bid >> 3;                      // 0..127
    const int mt = ((x >> 1) << 2) + (q & 3) + (((q >> 5) & 1) << 4);
    const int nt = ((x & 1) << 3) + ((q >> 2) & 7) + (((q >> 6) & 1) << 4);
    const int m0 = mt * BM;
    const int n0 = nt * BN;

    const int tid = threadIdx.x;
    const int lane = tid & 63;
    const int wid = tid >> 6;              // 0..7
    const int wm = wid >> 2, wn = wid & 3; // 2 x 4 wave grid
    const int lane15 = lane & 15, laneq = lane >> 4;

    // --- staging addresses ---
    const int G0 = tid, G1 = 512 + tid;
    const int r0 = G0 >> 3, r1 = G1 >> 3;
    const int c0 = (G0 & 7) ^ (r0 & 7), c1 = (G1 & 7) ^ (r1 & 7);
    const size_t aoff0 = (size_t)(m0 + r0) * K_DIM + c0 * 8;
    const size_t aoff1 = (size_t)(m0 + r1) * K_DIM + c1 * 8;
    const size_t boff0 = (size_t)(n0 + r0) * K_DIM + c0 * 8;
    const size_t boff1 = (size_t)(n0 + r1) * K_DIM + c1 * 8;
    const int dq0 = G0 * 16, dq1 = G1 * 16;
    const size_t HOFF = (size_t)128 * K_DIM;

#define STAGE_A(gt, hh) do { \
        char* _d = (char*)&lds_a[(gt) & 1][hh][0]; \
        async_copy16(A + aoff0 + (size_t)(hh) * HOFF + (size_t)(gt) * BK, _d + dq0); \
        async_copy16(A + aoff1 + (size_t)(hh) * HOFF + (size_t)(gt) * BK, _d + dq1); \
    } while (0)
#define STAGE_B(gt, hh) do { \
        char* _d = (char*)&lds_b[(gt) & 1][hh][0]; \
        async_copy16(Bt + boff0 + (size_t)(hh) * HOFF + (size_t)(gt) * BK, _d + dq0); \
        async_copy16(Bt + boff1 + (size_t)(hh) * HOFF + (size_t)(gt) * BK, _d + dq1); \
    } while (0)

    // --- swizzled ds_read base offsets (row&7 == lane15&7 for all fragments) ---
    const int xa = lane15 & 7;
    const int oa0 = (wm * 64 + lane15) * 128 + (((0 * 4 + laneq) ^ xa) * 16);
    const int oa1 = (wm * 64 + lane15) * 128 + (((1 * 4 + laneq) ^ xa) * 16);
    const int ob0 = (wn * 32 + lane15) * 128 + (((0 * 4 + laneq) ^ xa) * 16);
    const int ob1 = (wn * 32 + lane15) * 128 + (((1 * 4 + laneq) ^ xa) * 16);

    f32x4 acc[8][4];
#pragma unroll
    for (int i = 0; i < 8; ++i)
#pragma unroll
        for (int j = 0; j < 4; ++j) acc[i][j] = (f32x4){0.f, 0.f, 0.f, 0.f};

    short8 afX[4][2], afY[4][2], bfA[2][2], bfB[2][2], bf1[2][2];

    // --- prologue ---
    STAGE_A(0, 0); STAGE_A(0, 1); STAGE_B(0, 0); STAGE_B(0, 1);   // 8 loads
    STAGE_B(1, 0); STAGE_B(1, 1);                                 // +4 = 12
    asm volatile("s_waitcnt vmcnt(4)" ::: "memory");   // tile0 resident; B(1) in flight
    BAR();
    read_a((const char*)&lds_a[0][0][0], oa0, oa1, afX);   // A0(0)
    read_b((const char*)&lds_b[0][0][0], ob0, ob1, bfA);   // B0(0)

#define KITER(g, bf0c, bf0n) do { \
        const int d = (g) & 1; \
        /* P1: compute m0n0(afX,bf0c); read B1(g); stage A(g+1) */ \
        read_b((const char*)&lds_b[d][1][0], ob0, ob1, bf1); \
        if ((g) + 1 < NT) { STAGE_A((g) + 1, 0); STAGE_A((g) + 1, 1); } \
        BAR(); LGKM(4); \
        mfma16(afX, bf0c, acc, 0, 0); \
        /* P2: compute m0n1(afX,bf1); read A1(g) */ \
        read_a((const char*)&lds_a[d][1][0], oa0, oa1, afY); \
        BAR(); LGKM(8); \
        mfma16(afX, bf1, acc, 0, 2); \
        /* P3: compute m1n1(afY,bf1); stage B(g+2,0) */ \
        if ((g) + 2 < NT) STAGE_B((g) + 2, 0); \
        BAR(); LGKM(0); \
        mfma16(afY, bf1, acc, 4, 2); \
        /* P4: compute m1n0(afY,bf0c); stage B(g+2,1); vmcnt; read next tile */ \
        if ((g) + 2 < NT) STAGE_B((g) + 2, 1); \
        if ((g) < NT - 2) { asm volatile("s_waitcnt vmcnt(4)" ::: "memory"); } \
        else              { asm volatile("s_waitcnt vmcnt(0)" ::: "memory"); } \
        __builtin_amdgcn_sched_barrier(0); \
        if ((g) + 1 < NT) { \
            read_a((const char*)&lds_a[1 - d][0][0], oa0, oa1, afX); \
            read_b((const char*)&lds_b[1 - d][0][0], ob0, ob1, bf0n); \
        } \
        BAR(); \
        mfma16(afY, bf0c, acc, 4, 0); \
    } while (0)

    for (int g = 0; g < NT; g += 2) {
        KITER(g, bfA, bfB);
        KITER(g + 1, bfB, bfA);
    }
#undef KITER

    // --- epilogue: bias + f32 store ---
#pragma unroll
    for (int ig = 0; ig < 8; ++ig) {
        int row = m0 + (ig >> 2) * 128 + wm * 64 + (ig & 3) * 16 + laneq * 4;
#pragma unroll
        for (int jg = 0; jg < 4; ++jg) {
            int col = n0 + (jg >> 1) * 128 + wn * 32 + (jg & 1) * 16 + lane15;
            float bv = bias[col];
            f32x4 v = acc[ig][jg];
#pragma unroll
            for (int q2 = 0; q2 < 4; ++q2)
                C[(size_t)(row + q2) * N_DIM + col] = v[q2] + bv;
        }
    }
#undef STAGE_A
#undef STAGE_B
}

extern "C" void kernel_launch(void* const* d_in, const int* in_sizes, int n_in,
                              void* d_out, int out_size, void* d_ws, size_t ws_size,
                              hipStream_t stream) {
    const float* x = (const float*)d_in[0];
    const float* codebook = (const float*)d_in[1];
    const int* indices = (const int*)d_in[2];      // harness: integer -> int32
    const float* bias = (const float*)d_in[3];
    float* out = (float*)d_out;

    ushort_t* A  = (ushort_t*)d_ws;                               // 32 MB
    ushort_t* Bt = (ushort_t*)d_ws + (size_t)M_DIM * K_DIM;       // 32 MB

    convert_x<<<dim3(M_DIM * K_DIM / (256 * 8)), 256, 0, stream>>>(x, A);
    dequant_wt<<<dim3(1024, 8), 256, 0, stream>>>(indices, codebook, Bt);
    gemm_256_8phase<<<dim3((M_DIM / BM) * (N_DIM / BN)), 512, 0, stream>>>(A, Bt, bias, out);
}